// Round 9
// baseline (511.755 us; speedup 1.0000x reference)
//
#include <hip/hip_runtime.h>
#include <math.h>

// ---------------------------------------------------------------------------
// CoTracker correlation-embedding pipeline, bf16 MFMA, HWC-padded fmaps.
// Round 8: R7 (register-synthesized W for MFMA2 bilinear, 3 blocks/CU)
// + restored pcT pad-column zeroing (R7's NaN: 0 x uninit-Inf in MFMA2 K-pad).
// Inputs: 0:fmaps0 1:track0 2:fmaps1 3:track1 4:fmaps2 5:track2 6:fmaps3
//         7:track3 8:coords 9:vis 10:conf 11:w1 12:b1 13:w2 14:b2 15:time_emb
// Output: (1,N,8,1110) f32.
// ---------------------------------------------------------------------------

#define SN 8
#define NN 1024
#define CC 128
#define K1P 2432
#define H1 384
#define H2 256
#define DOUT 1110

typedef short bf16x8 __attribute__((ext_vector_type(8)));
typedef float f32x4 __attribute__((ext_vector_type(4)));
typedef unsigned u32x4 __attribute__((ext_vector_type(4)));

__device__ inline unsigned short f2b(float x) {  // RTNE f32 -> bf16
    union { float f; unsigned u; } v; v.f = x;
    unsigned r = v.u + 0x7FFFu + ((v.u >> 16) & 1u);
    return (unsigned short)(r >> 16);
}
__device__ inline void gll16(const void* g, void* l) {
    __builtin_amdgcn_global_load_lds(
        (const __attribute__((address_space(1))) void*)g,
        (__attribute__((address_space(3))) void*)l, 16, 0, 0);
}
// XOR-swizzled LDS index (shorts) for [rows][128] bf16 MFMA operand tiles.
__device__ inline int swz(int row, int g) {
    return row * 128 + ((g ^ (row & 7)) << 3);
}
// W element select: d = k - b0 -> taps {0:w00, 1:w10, 10:w01, 11:w11}
__device__ inline unsigned selw(int d, unsigned W00, unsigned W10,
                                unsigned W01, unsigned W11) {
    return d == 0 ? W00 : d == 1 ? W10 : d == 10 ? W01 : d == 11 ? W11 : 0u;
}

// ---------------------------------------------------------------------------
// fmap fp32 (S,C,H,W) -> bf16 HWC padded (S, H+8, W+8, C), border replicate.
// ---------------------------------------------------------------------------
__global__ __launch_bounds__(256) void conv_fmap_kernel(
    const float* __restrict__ in, unsigned short* __restrict__ outp,
    int H, int W)
{
    const int Hp = H + 8, Wp = W + 8;
    const int s = blockIdx.x / Hp, yp = blockIdx.x % Hp;
    const int y = min(max(yp - 4, 0), H - 1);
    const float* src = in + (size_t)s * CC * H * W + (size_t)y * W;
    unsigned short* dst = outp + ((size_t)s * Hp + yp) * Wp * CC;
    for (int idx = threadIdx.x; idx < Wp * CC; idx += 256) {
        int xp = idx >> 7, c = idx & 127;
        int x = min(max(xp - 4, 0), W - 1);
        dst[idx] = f2b(src[(size_t)c * H * W + x]);
    }
}

// ---------------------------------------------------------------------------
// Kernel A (fused over levels): block -> (g = blk>>10, n = blk&1023).
// Per s: [vmcnt(16)+bar] MFMA1: pcT[ij][p] = trk . patch^T
//        [lgkm bar] gll16 next patch; MFMA2: vol[ab][ij] = W(reg) . pcT^T;
//        16 u16 stores/thread (invalid -> zero into K-pad).
// LDS 49.3KB -> 3 blocks/CU.
// ---------------------------------------------------------------------------
__global__ __launch_bounds__(256, 3) void sample_vol_kernel(
    const unsigned short* __restrict__ fq0, const unsigned short* __restrict__ fq1,
    const unsigned short* __restrict__ fq2, const unsigned short* __restrict__ fq3,
    const float* __restrict__ tk0, const float* __restrict__ tk1,
    const float* __restrict__ tk2, const float* __restrict__ tk3,
    const float* __restrict__ coords,        // (8, N, 2) f32
    unsigned short* __restrict__ vol,        // (n_lv*8*N, 2432) bf16
    int lv0)
{
    __shared__ __align__(16) unsigned short patch[80 * 128]; // 20 KB
    __shared__ __align__(16) unsigned short trk[64 * 128];   // 16 KB
    __shared__ __align__(16) unsigned short pcT[64 * 104];   // 13 KB
    const int n = blockIdx.x & 1023, g = blockIdx.x >> 10;
    const int lvl = lv0 + g;
    const unsigned short* fpad = (lvl == 0) ? fq0 : (lvl == 1) ? fq1
                               : (lvl == 2) ? fq2 : fq3;
    const float* track = (lvl == 0) ? tk0 : (lvl == 1) ? tk1
                       : (lvl == 2) ? tk2 : tk3;
    const int Wp = (128 >> lvl) + 8;
    const int t = threadIdx.x;
    const int lane = t & 63, wv = t >> 6;
    const int rsub = lane & 15, kq = lane >> 4;
    const float inv = 1.0f / (float)(1 << lvl);
    const size_t plane = (size_t)((96 >> lvl) + 8) * Wp * CC;

    // per-lane static patch-load offsets (pre-swizzled global granule)
    int poff[5], ldso[5];
    #pragma unroll
    for (int i = 0; i < 5; ++i) {
        int task64 = wv * 5 + i;
        int point = task64 * 4 + (lane >> 4);  // patch row 0..79
        int v = point / 10, xs = point - v * 10;
        int j = (lane & 15) ^ (point & 7);
        poff[i] = (v * Wp + xs) * CC + j * 8;
        ldso[i] = task64 * 512;
    }

    // A-operand row this lane supplies to MFMA2: ab_A = wv*16 + rsub
    const int abA = wv * 16 + rsub;
    const int wa = abA / 7, wb = abA - 7 * (abA / 7);
    const int b0base = wb * 10 + wa;  // + off at runtime

    // hoist all 8 coords into registers
    float cxa[SN], cya[SN];
    #pragma unroll
    for (int s = 0; s < SN; ++s) {
        float2 c2 = *(const float2*)&coords[((size_t)s * NN + n) * 2];
        cxa[s] = c2.x * inv; cya[s] = c2.y * inv;
    }

    // first patch issue (loads must be OLDEST in each wave's VMEM queue)
    int fx = (int)floorf(cxa[0]), fy = (int)floorf(cya[0]);
    int e = (fx - 3) & ~1;
    {
        const unsigned short* base = fpad + ((fy + 1) * Wp + (e + 4)) * CC;
        #pragma unroll
        for (int i = 0; i < 5; ++i) gll16(base + poff[i], &patch[ldso[i]]);
    }
    // track[n] -> trk LDS (swizzled), once
    for (int task = t; task < 49 * 16; task += 256) {
        int row = task >> 4, gg = task & 15;
        const float* srcp = &track[((size_t)row * NN + n) * CC + gg * 8];
        float4 f0 = *(const float4*)srcp;
        float4 f1 = *(const float4*)(srcp + 4);
        bf16x8 v8;
        v8[0] = f2b(f0.x); v8[1] = f2b(f0.y); v8[2] = f2b(f0.z); v8[3] = f2b(f0.w);
        v8[4] = f2b(f1.x); v8[5] = f2b(f1.y); v8[6] = f2b(f1.z); v8[7] = f2b(f1.w);
        *(bf16x8*)&trk[swz(row, gg)] = v8;
    }
    // prologue zeros: trk rows 49..63 AND pcT pad columns 80..103 (NaN guard:
    // MFMA2 reads K=96; 0 x uninit-Inf = NaN would poison valid rows).
    {
        unsigned* T32 = (unsigned*)trk;
        for (int i = t; i < 15 * 64; i += 256) T32[49 * 64 + i] = 0;
        unsigned* P32 = (unsigned*)pcT;
        for (int i = t; i < 64 * 12; i += 256) {
            int r = i / 12, c = i - 12 * r;
            P32[r * 52 + 40 + c] = 0;
        }
    }

    #pragma unroll
    for (int sl = 0; sl < SN; ++sl) {
        const float wx = cxa[sl] - (float)fx, wy = cya[sl] - (float)fy;
        const unsigned W00 = f2b((1.f - wx) * (1.f - wy));
        const unsigned W10 = f2b(wx * (1.f - wy));
        const unsigned W01 = f2b((1.f - wx) * wy);
        const unsigned W11 = f2b(wx * wy);
        const int b0 = b0base + (fx - 3 - e);

        // top barrier: patch landed (5 oldest VMEM of 21 outstanding)
        if (sl == 0) asm volatile("s_waitcnt vmcnt(0) lgkmcnt(0)" ::: "memory");
        else         asm volatile("s_waitcnt vmcnt(16) lgkmcnt(0)" ::: "memory");
        __builtin_amdgcn_sched_barrier(0);
        __builtin_amdgcn_s_barrier();
        __builtin_amdgcn_sched_barrier(0);

        // ---- PHASE A: MFMA1 pcT[ij][p] = trk(64x128) . patch(80x128)^T ----
        {
            f32x4 acc[5] = {};
            #pragma unroll
            for (int kk = 0; kk < 4; ++kk) {
                int gg = kk * 4 + kq;
                bf16x8 a = *(const bf16x8*)&trk[swz(wv * 16 + rsub, gg)];
                #pragma unroll
                for (int ti = 0; ti < 5; ++ti) {
                    bf16x8 b = *(const bf16x8*)&patch[swz(ti * 16 + rsub, gg)];
                    acc[ti] = __builtin_amdgcn_mfma_f32_16x16x32_bf16(a, b, acc[ti], 0, 0, 0);
                }
            }
            #pragma unroll
            for (int ti = 0; ti < 5; ++ti)
                #pragma unroll
                for (int r = 0; r < 4; ++r)
                    pcT[(wv * 16 + kq * 4 + r) * 104 + ti * 16 + rsub] = f2b(acc[ti][r]);
        }

        asm volatile("s_waitcnt lgkmcnt(0)" ::: "memory");
        __builtin_amdgcn_s_barrier();
        __builtin_amdgcn_sched_barrier(0);

        // ---- PHASE B: issue next-s patch loads FIRST (oldest in queue) ----
        if (sl + 1 < SN) {
            fx = (int)floorf(cxa[sl + 1]); fy = (int)floorf(cya[sl + 1]);
            e = (fx - 3) & ~1;
            const unsigned short* base =
                fpad + (size_t)(sl + 1) * plane + ((fy + 1) * Wp + (e + 4)) * CC;
            #pragma unroll
            for (int i = 0; i < 5; ++i) gll16(base + poff[i], &patch[ldso[i]]);
        }
        __builtin_amdgcn_sched_barrier(0);

        // ---- MFMA2: vol[ab][ij] = W(49x96, registers) . pcT(64x96)^T ----
        {
            f32x4 acc2[4] = {};
            #pragma unroll
            for (int kk = 0; kk < 3; ++kk) {
                // synthesize A-fragment: W[abA][kk*32+kq*8 .. +7]
                u32x4 aw;
                #pragma unroll
                for (int j = 0; j < 4; ++j) {
                    int p = kk * 32 + kq * 8 + 2 * j;
                    unsigned lo = selw(p - b0,     W00, W10, W01, W11);
                    unsigned hi = selw(p + 1 - b0, W00, W10, W01, W11);
                    aw[j] = lo | (hi << 16);
                }
                bf16x8 a = __builtin_bit_cast(bf16x8, aw);
                int g2 = (kk * 4 + kq) * 8;
                #pragma unroll
                for (int ni = 0; ni < 4; ++ni) {
                    bf16x8 b = *(const bf16x8*)&pcT[(ni * 16 + rsub) * 104 + g2];
                    acc2[ni] = __builtin_amdgcn_mfma_f32_16x16x32_bf16(a, b, acc2[ni], 0, 0, 0);
                }
            }
            // 16 unguarded u16 stores per thread (exact per-wave VMEM count)
            unsigned short* vrow = vol + ((size_t)(g * SN + sl) * NN + n) * K1P;
            #pragma unroll
            for (int ni = 0; ni < 4; ++ni) {
                int ij = ni * 16 + rsub;
                #pragma unroll
                for (int r = 0; r < 4; ++r) {
                    int ab = wv * 16 + kq * 4 + r;
                    bool valid = (ab < 49) && (ij < 49);
                    int addr = valid ? (ab * 49 + ij)
                                     : (2401 + (lane + (ni * 4 + r) * 7) % 31);
                    unsigned short val = valid ? f2b(acc2[ni][r]) : (unsigned short)0;
                    vrow[addr] = val;
                }
            }
        }
    }
}

// ---------------------------------------------------------------------------
// GEMM1: H = gelu(vol @ w1 + b1).  (rows x 2432) @ (2432 x 384) bf16.
// 3-buffer counted-vmcnt pipeline.
// ---------------------------------------------------------------------------
__global__ __launch_bounds__(256, 3) void gemm1_kernel(
    const unsigned short* __restrict__ A,   // rows x 2432
    const unsigned short* __restrict__ Bt,  // 384 x 2432 (= w1^T)
    const float* __restrict__ bias,
    unsigned short* __restrict__ Hout)      // rows x 384
{
    __shared__ __align__(16) unsigned short As[3 * 128 * 32];
    __shared__ __align__(16) unsigned short Bs[3 * 128 * 32];
    const int h = blockIdx.x, q = gridDim.x >> 3;
    const int l = (h & 7) * q + (h >> 3);
    const int m0 = (l / 3) * 128, n0 = (l % 3) * 128;
    const int t = threadIdx.x, lane = t & 63, wv = t >> 6;
    const int wm = wv >> 1, wn = wv & 1;
    const int rsub = lane & 15, kq = lane >> 4;

    const int rA0 = t >> 2, sA0 = (t & 3) ^ ((rA0 >> 1) & 3);
    const int rA1 = (t + 256) >> 2, sA1 = ((t + 256) & 3) ^ ((rA1 >> 1) & 3);
    const unsigned short* gA0 = A  + (size_t)(m0 + rA0) * K1P + sA0 * 8;
    const unsigned short* gA1 = A  + (size_t)(m0 + rA1) * K1P + sA1 * 8;
    const unsigned short* gB0 = Bt + (size_t)(n0 + rA0) * K1P + sA0 * 8;
    const unsigned short* gB1 = Bt + (size_t)(n0 + rA1) * K1P + sA1 * 8;
    const int chunk0 = (t & ~63) * 8, chunk1 = (256 + (t & ~63)) * 8;

    f32x4 acc[4][4] = {};

    const int NSTEP = K1P / 32;  // 76
    #pragma unroll
    for (int p = 0; p < 3; ++p) {
        size_t ko = (size_t)p * 32;
        int lb = p * 4096;
        gll16(gA0 + ko, &As[lb + chunk0]); gll16(gA1 + ko, &As[lb + chunk1]);
        gll16(gB0 + ko, &Bs[lb + chunk0]); gll16(gB1 + ko, &Bs[lb + chunk1]);
    }
    int cur = 0;
    for (int st = 0; st < NSTEP; ++st) {
        const int rem = NSTEP - 1 - st;
        if (rem >= 2)      asm volatile("s_waitcnt vmcnt(8)" ::: "memory");
        else if (rem == 1) asm volatile("s_waitcnt vmcnt(4)" ::: "memory");
        else               asm volatile("s_waitcnt vmcnt(0)" ::: "memory");
        __builtin_amdgcn_s_barrier();
        __builtin_amdgcn_sched_barrier(0);
        const int lb = cur * 4096;
        bf16x8 af[4], bfr[4];
        #pragma unroll
        for (int mi = 0; mi < 4; ++mi) {
            int r = wm * 64 + mi * 16 + rsub;
            int phys = r * 4 + (kq ^ ((r >> 1) & 3));
            af[mi] = *(const bf16x8*)&As[lb + phys * 8];
        }
        #pragma unroll
        for (int ni = 0; ni < 4; ++ni) {
            int r = wn * 64 + ni * 16 + rsub;
            int phys = r * 4 + (kq ^ ((r >> 1) & 3));
            bfr[ni] = *(const bf16x8*)&Bs[lb + phys * 8];
        }
        #pragma unroll
        for (int mi = 0; mi < 4; ++mi)
            #pragma unroll
            for (int ni = 0; ni < 4; ++ni)
                acc[mi][ni] = __builtin_amdgcn_mfma_f32_16x16x32_bf16(
                    af[mi], bfr[ni], acc[mi][ni], 0, 0, 0);
        __builtin_amdgcn_sched_barrier(0);
        __builtin_amdgcn_s_barrier();
        __builtin_amdgcn_sched_barrier(0);
        if (st + 3 < NSTEP) {
            size_t ko = (size_t)(st + 3) * 32;
            gll16(gA0 + ko, &As[lb + chunk0]);
            gll16(gA1 + ko, &As[lb + chunk1]);
            gll16(gB0 + ko, &Bs[lb + chunk0]);
            gll16(gB1 + ko, &Bs[lb + chunk1]);
        }
        cur = (cur == 2) ? 0 : cur + 1;
    }
    #pragma unroll
    for (int mi = 0; mi < 4; ++mi) {
        int row = m0 + wm * 64 + mi * 16 + kq * 4;
        #pragma unroll
        for (int ni = 0; ni < 4; ++ni) {
            int col = n0 + wn * 64 + ni * 16 + rsub;
            float bcol = bias[col];
            #pragma unroll
            for (int r = 0; r < 4; ++r) {
                float x = acc[mi][ni][r] + bcol;
                float gg = 0.5f * x * (1.f + erff(x * 0.70710678118654752f));
                Hout[(size_t)(row + r) * H1 + col] = f2b(gg);
            }
        }
    }
}

// ---------------------------------------------------------------------------
// GEMM2: out slice = H @ w2 + b2 + time_emb.  (rows x 384) @ (384 x 256).
// ---------------------------------------------------------------------------
__global__ __launch_bounds__(256, 3) void gemm2_kernel(
    const unsigned short* __restrict__ A,   // rows x 384
    const unsigned short* __restrict__ Bt,  // 256 x 384 (= w2^T)
    const float* __restrict__ bias,
    const float* __restrict__ te,           // (8, 1110)
    float* __restrict__ out,                // (N, 8, 1110)
    int lv0)
{
    __shared__ __align__(16) unsigned short As[3 * 128 * 32];
    __shared__ __align__(16) unsigned short Bs[3 * 128 * 32];
    const int h = blockIdx.x, q = gridDim.x >> 3;
    const int l = (h & 7) * q + (h >> 3);
    const int m0 = (l >> 1) * 128, n0 = (l & 1) * 128;
    const int t = threadIdx.x, lane = t & 63, wv = t >> 6;
    const int wm = wv >> 1, wn = wv & 1;
    const int rsub = lane & 15, kq = lane >> 4;

    const int rA0 = t >> 2, sA0 = (t & 3) ^ ((rA0 >> 1) & 3);
    const int rA1 = (t + 256) >> 2, sA1 = ((t + 256) & 3) ^ ((rA1 >> 1) & 3);
    const unsigned short* gA0 = A  + (size_t)(m0 + rA0) * H1 + sA0 * 8;
    const unsigned short* gA1 = A  + (size_t)(m0 + rA1) * H1 + sA1 * 8;
    const unsigned short* gB0 = Bt + (size_t)(n0 + rA0) * H1 + sA0 * 8;
    const unsigned short* gB1 = Bt + (size_t)(n0 + rA1) * H1 + sA1 * 8;
    const int chunk0 = (t & ~63) * 8, chunk1 = (256 + (t & ~63)) * 8;

    f32x4 acc[4][4] = {};

    const int NSTEP = H1 / 32;  // 12
    #pragma unroll
    for (int p = 0; p < 3; ++p) {
        size_t ko = (size_t)p * 32;
        int lb = p * 4096;
        gll16(gA0 + ko, &As[lb + chunk0]); gll16(gA1 + ko, &As[lb + chunk1]);
        gll16(gB0 + ko, &Bs[lb + chunk0]); gll16(gB1 + ko, &Bs[lb + chunk1]);
    }
    int cur = 0;
    for (int st = 0; st < NSTEP; ++st) {
        const int rem = NSTEP - 1 - st;
        if (rem >= 2)      asm volatile("s_waitcnt vmcnt(8)" ::: "memory");
        else if (rem == 1) asm volatile("s_waitcnt vmcnt(4)" ::: "memory");
        else               asm volatile("s_waitcnt vmcnt(0)" ::: "memory");
        __builtin_amdgcn_s_barrier();
        __builtin_amdgcn_sched_barrier(0);
        const int lb = cur * 4096;
        bf16x8 af[4], bfr[4];
        #pragma unroll
        for (int mi = 0; mi < 4; ++mi) {
            int r = wm * 64 + mi * 16 + rsub;
            int phys = r * 4 + (kq ^ ((r >> 1) & 3));
            af[mi] = *(const bf16x8*)&As[lb + phys * 8];
        }
        #pragma unroll
        for (int ni = 0; ni < 4; ++ni) {
            int r = wn * 64 + ni * 16 + rsub;
            int phys = r * 4 + (kq ^ ((r >> 1) & 3));
            bfr[ni] = *(const bf16x8*)&Bs[lb + phys * 8];
        }
        #pragma unroll
        for (int mi = 0; mi < 4; ++mi)
            #pragma unroll
            for (int ni = 0; ni < 4; ++ni)
                acc[mi][ni] = __builtin_amdgcn_mfma_f32_16x16x32_bf16(
                    af[mi], bfr[ni], acc[mi][ni], 0, 0, 0);
        __builtin_amdgcn_sched_barrier(0);
        __builtin_amdgcn_s_barrier();
        __builtin_amdgcn_sched_barrier(0);
        if (st + 3 < NSTEP) {
            size_t ko = (size_t)(st + 3) * 32;
            gll16(gA0 + ko, &As[lb + chunk0]);
            gll16(gA1 + ko, &As[lb + chunk1]);
            gll16(gB0 + ko, &Bs[lb + chunk0]);
            gll16(gB1 + ko, &Bs[lb + chunk1]);
        }
        cur = (cur == 2) ? 0 : cur + 1;
    }
    #pragma unroll
    for (int mi = 0; mi < 4; ++mi) {
        int rowb = m0 + wm * 64 + mi * 16 + kq * 4;
        #pragma unroll
        for (int ni = 0; ni < 4; ++ni) {
            int col = n0 + wn * 64 + ni * 16 + rsub;
            float bcol = bias[col];
            #pragma unroll
            for (int r = 0; r < 4; ++r) {
                int row = rowb + r;
                int g = row >> 13, s = (row >> 10) & 7, n = row & 1023;
                int dcol = 2 + (lv0 + g) * H2 + col;
                out[((size_t)n * SN + s) * DOUT + dcol] =
                    acc[mi][ni][r] + bcol + te[s * DOUT + dcol];
            }
        }
    }
}

// ---------------------------------------------------------------------------
// Transpose + bf16-convert: in (K x Nw f32) -> out (Nw x Kp bf16), zero-pad.
// ---------------------------------------------------------------------------
__global__ __launch_bounds__(256) void conv_t_kernel(
    const float* __restrict__ in, unsigned short* __restrict__ outp,
    int K, int Nw, int Kp)
{
    __shared__ float tile[32][33];
    const int kb = blockIdx.x * 32, nb = blockIdx.y * 32;
    const int tx = threadIdx.x & 31, ty = threadIdx.x >> 5;
    #pragma unroll
    for (int i = 0; i < 32; i += 8) {
        int k = kb + ty + i, nn = nb + tx;
        tile[ty + i][tx] = (k < K && nn < Nw) ? in[(size_t)k * Nw + nn] : 0.f;
    }
    __syncthreads();
    #pragma unroll
    for (int i = 0; i < 32; i += 8) {
        int nn = nb + ty + i, k = kb + tx;
        if (nn < Nw) outp[(size_t)nn * Kp + k] = f2b(tile[tx][ty + i]);
    }
}

// Kernel D: vis, conf, rel_emb(84) + time_emb.
__global__ __launch_bounds__(128) void tail_kernel(
    const float* __restrict__ coords, const float* __restrict__ vis,
    const float* __restrict__ conf, const float* __restrict__ te,
    float* __restrict__ out)
{
    const int b = blockIdx.x;
    const int n = b >> 3, s = b & 7;
    const int d = threadIdx.x;
    if (d >= 86) return;
    const size_t ob = (size_t)b * DOUT;
    if (d == 0) {
        out[ob + 0] = vis[(size_t)s * NN + n] + te[s * DOUT + 0];
    } else if (d == 1) {
        out[ob + 1] = conf[(size_t)s * NN + n] + te[s * DOUT + 1];
    } else {
        int rd = d - 2;
        float cx = coords[((size_t)s * NN + n) * 2 + 0];
        float cy = coords[((size_t)s * NN + n) * 2 + 1];
        float rfx = 0.f, rfy = 0.f, rbx = 0.f, rby = 0.f;
        if (s < SN - 1) {
            rfx = cx - coords[((size_t)(s + 1) * NN + n) * 2 + 0];
            rfy = cy - coords[((size_t)(s + 1) * NN + n) * 2 + 1];
        }
        if (s > 0) {
            rbx = cx - coords[((size_t)(s - 1) * NN + n) * 2 + 0];
            rby = cy - coords[((size_t)(s - 1) * NN + n) * 2 + 1];
        }
        float r4[4] = {rfx / 128.f, rfy / 96.f, rbx / 128.f, rby / 96.f};
        float val;
        if (rd < 4) {
            val = r4[rd];
        } else if (rd < 44) {
            int q = rd - 4; int deg = q >> 2, comp = q & 3;
            val = sinf(r4[comp] * (float)(1 << deg));
        } else {
            int q = rd - 44; int deg = q >> 2, comp = q & 3;
            val = sinf(r4[comp] * (float)(1 << deg) + 1.57079632679489662f);
        }
        int od = 1026 + rd;
        out[ob + od] = val + te[s * DOUT + od];
    }
}

extern "C" void kernel_launch(void* const* d_in, const int* in_sizes, int n_in,
                              void* d_out, int out_size, void* d_ws, size_t ws_size,
                              hipStream_t stream) {
    const float* fmaps[4] = {(const float*)d_in[0], (const float*)d_in[2],
                             (const float*)d_in[4], (const float*)d_in[6]};
    const float* track[4] = {(const float*)d_in[1], (const float*)d_in[3],
                             (const float*)d_in[5], (const float*)d_in[7]};
    const float* coords = (const float*)d_in[8];
    const float* vis    = (const float*)d_in[9];
    const float* conf   = (const float*)d_in[10];
    const float* w1     = (const float*)d_in[11];
    const float* b1     = (const float*)d_in[12];
    const float* w2     = (const float*)d_in[13];
    const float* b2     = (const float*)d_in[14];
    const float* te     = (const float*)d_in[15];
    float* out = (float*)d_out;

    const int Hs[4] = {96, 48, 24, 12};
    const int Ws[4] = {128, 64, 32, 16};

    // ---- workspace layout ----
    char* wsb = (char*)d_ws;
    unsigned short* w1t = (unsigned short*)wsb;
    size_t off = (size_t)H1 * K1P * 2;
    unsigned short* w2t = (unsigned short*)(wsb + off);
    off += (size_t)H2 * H1 * 2;
    unsigned short* fpad[4];
    for (int l = 0; l < 4; ++l) {
        fpad[l] = (unsigned short*)(wsb + off);
        off += (size_t)SN * (Hs[l] + 8) * (Ws[l] + 8) * CC * 2;
    }
    off += 512;  // slack
    const size_t fixed = off;
    int n_lv = 4;
    while (n_lv > 1 &&
           fixed + (size_t)n_lv * SN * NN * (K1P + H1) * 2 > ws_size)
        n_lv >>= 1;
    unsigned short* volb = (unsigned short*)(wsb + fixed);
    unsigned short* hb   = volb + (size_t)n_lv * SN * NN * K1P;

    // ---- weight prep + fmap conversion ----
    conv_t_kernel<<<dim3(K1P / 32, H1 / 32), 256, 0, stream>>>(w1, w1t, 2401, H1, K1P);
    conv_t_kernel<<<dim3(H1 / 32, H2 / 32), 256, 0, stream>>>(w2, w2t, H1, H2, H1);
    for (int l = 0; l < 4; ++l)
        conv_fmap_kernel<<<SN * (Hs[l] + 8), 256, 0, stream>>>(
            fmaps[l], fpad[l], Hs[l], Ws[l]);

    for (int lv0 = 0; lv0 < 4; lv0 += n_lv) {
        sample_vol_kernel<<<n_lv * NN, 256, 0, stream>>>(
            fpad[0], fpad[1], fpad[2], fpad[3],
            track[0], track[1], track[2], track[3],
            coords, volb, lv0);
        const int rows = n_lv * SN * NN;
        gemm1_kernel<<<(rows / 128) * 3, 256, 0, stream>>>(volb, w1t, b1, hb);
        gemm2_kernel<<<(rows / 128) * 2, 256, 0, stream>>>(hb, w2t, b2, te, out, lv0);
    }
    tail_kernel<<<SN * NN, 128, 0, stream>>>(coords, vis, conf, te, out);
}

// Round 10
// 387.601 us; speedup vs baseline: 1.3203x; 1.3203x over previous
//
#include <hip/hip_runtime.h>
#include <math.h>

// ---------------------------------------------------------------------------
// CoTracker correlation-embedding pipeline, bf16 MFMA, HWC-padded fmaps.
// Round 9: REVERT sample_vol to the validated R5 design (MFMA corr + VALU
// bilinear w/ register LUT, 47.5KB LDS, 3 blocks/CU). Single experiment:
// gemm1/gemm2 deepened to 4-buffer counted-vmcnt (prefetch distance 3).
// Inputs: 0:fmaps0 1:track0 2:fmaps1 3:track1 4:fmaps2 5:track2 6:fmaps3
//         7:track3 8:coords 9:vis 10:conf 11:w1 12:b1 13:w2 14:b2 15:time_emb
// Output: (1,N,8,1110) f32.
// ---------------------------------------------------------------------------

#define SN 8
#define NN 1024
#define CC 128
#define K1P 2432
#define H1 384
#define H2 256
#define DOUT 1110

typedef short bf16x8 __attribute__((ext_vector_type(8)));
typedef float f32x4 __attribute__((ext_vector_type(4)));

__device__ inline unsigned short f2b(float x) {  // RTNE f32 -> bf16
    union { float f; unsigned u; } v; v.f = x;
    unsigned r = v.u + 0x7FFFu + ((v.u >> 16) & 1u);
    return (unsigned short)(r >> 16);
}
__device__ inline float b2f(unsigned short u) {
    union { unsigned u; float f; } v; v.u = (unsigned)u << 16; return v.f;
}
__device__ inline void gll16(const void* g, void* l) {
    __builtin_amdgcn_global_load_lds(
        (const __attribute__((address_space(1))) void*)g,
        (__attribute__((address_space(3))) void*)l, 16, 0, 0);
}
// XOR-swizzled LDS index (shorts) for [rows][128] bf16 MFMA operand tiles.
__device__ inline int swz(int row, int g) {
    return row * 128 + ((g ^ (row & 7)) << 3);
}

// ---------------------------------------------------------------------------
// fmap fp32 (S,C,H,W) -> bf16 HWC padded (S, H+8, W+8, C), border replicate.
// ---------------------------------------------------------------------------
__global__ __launch_bounds__(256) void conv_fmap_kernel(
    const float* __restrict__ in, unsigned short* __restrict__ outp,
    int H, int W)
{
    const int Hp = H + 8, Wp = W + 8;
    const int s = blockIdx.x / Hp, yp = blockIdx.x % Hp;
    const int y = min(max(yp - 4, 0), H - 1);
    const float* src = in + (size_t)s * CC * H * W + (size_t)y * W;
    unsigned short* dst = outp + ((size_t)s * Hp + yp) * Wp * CC;
    for (int idx = threadIdx.x; idx < Wp * CC; idx += 256) {
        int xp = idx >> 7, c = idx & 127;
        int x = min(max(xp - 4, 0), W - 1);
        dst[idx] = f2b(src[(size_t)c * H * W + x]);
    }
}

// ---------------------------------------------------------------------------
// Kernel A (fused over levels): block -> (g = blk>>10, n = blk&1023).
// trk loaded once (swizzled). Per s (fully unrolled):
//   patch (80x128 bf16, pre-swizzled global src) via global_load_lds
//   (prefetched during prev bilinear) -> MFMA pc[80][64] -> pcL bf16 [80][66]
//   -> bilinear on output domain (register LUT, u16 taps) -> vol row packed.
// LDS ~46.3KB -> 3 blocks/CU.
// ---------------------------------------------------------------------------
__global__ __launch_bounds__(256, 3) void sample_vol_kernel(
    const unsigned short* __restrict__ fq0, const unsigned short* __restrict__ fq1,
    const unsigned short* __restrict__ fq2, const unsigned short* __restrict__ fq3,
    const float* __restrict__ tk0, const float* __restrict__ tk1,
    const float* __restrict__ tk2, const float* __restrict__ tk3,
    const float* __restrict__ coords,        // (8, N, 2) f32
    unsigned short* __restrict__ vol,        // (n_lv*8*N, 2432) bf16
    int lv0)
{
    __shared__ __align__(16) unsigned short patch[80 * 128]; // 20 KB
    __shared__ __align__(16) unsigned short trk[64 * 128];   // 16 KB
    __shared__ __align__(16) unsigned short pcL[80 * 66];    // 10.3 KB
    const int n = blockIdx.x & 1023, g = blockIdx.x >> 10;
    const int lvl = lv0 + g;
    const unsigned short* fpad = (lvl == 0) ? fq0 : (lvl == 1) ? fq1
                               : (lvl == 2) ? fq2 : fq3;
    const float* track = (lvl == 0) ? tk0 : (lvl == 1) ? tk1
                       : (lvl == 2) ? tk2 : tk3;
    const int Wp = (128 >> lvl) + 8;
    const int t = threadIdx.x;
    const int lane = t & 63, wv = t >> 6;
    const int rsub = lane & 15, kq = lane >> 4;
    const float inv = 1.0f / (float)(1 << lvl);
    const size_t plane = (size_t)((96 >> lvl) + 8) * Wp * CC;

    // per-lane static patch-load offsets (pre-swizzled global granule)
    int poff[5], ldso[5];
    #pragma unroll
    for (int i = 0; i < 5; ++i) {
        int task64 = wv * 5 + i;
        int point = task64 * 4 + (lane >> 4);  // patch row 0..79
        int v = point / 10, xs = point - v * 10;
        int j = (lane & 15) ^ (point & 7);
        poff[i] = (v * Wp + xs) * CC + j * 8;
        ldso[i] = task64 * 512;
    }

    // hoist all 8 coords into registers
    float cxa[SN], cya[SN];
    #pragma unroll
    for (int s = 0; s < SN; ++s) {
        float2 c2 = *(const float2*)&coords[((size_t)s * NN + n) * 2];
        cxa[s] = c2.x * inv; cya[s] = c2.y * inv;
    }

    // register LUT for bilinear output decomposition (divs once per thread)
    unsigned lutA[5], lutB[5];
    #pragma unroll
    for (int i = 0; i < 5; ++i) {
        int d = t + i * 256;
        int o0 = 2 * d, o1 = 2 * d + 1;
        lutA[i] = 0xFFFFFFFFu; lutB[i] = 0xFFFFFFFFu;
        if (o0 < 2401) {
            int ab = o0 / 49, ij = o0 - 49 * ab, a = ab / 7, b = ab - 7 * a;
            lutA[i] = (unsigned)((b * 10 + a) * 66 + ij);
        }
        if (o1 < 2401) {
            int ab = o1 / 49, ij = o1 - 49 * ab, a = ab / 7, b = ab - 7 * a;
            lutB[i] = (unsigned)((b * 10 + a) * 66 + ij);
        }
    }

    // first patch issue
    int fx = (int)floorf(cxa[0]), fy = (int)floorf(cya[0]);
    int e = (fx - 3) & ~1;
    {
        const unsigned short* base = fpad + ((fy + 1) * Wp + (e + 4)) * CC;
        #pragma unroll
        for (int i = 0; i < 5; ++i) gll16(base + poff[i], &patch[ldso[i]]);
    }
    // track[n] -> trk LDS (swizzled), once
    for (int task = t; task < 49 * 16; task += 256) {
        int row = task >> 4, gg = task & 15;
        const float* srcp = &track[((size_t)row * NN + n) * CC + gg * 8];
        float4 f0 = *(const float4*)srcp;
        float4 f1 = *(const float4*)(srcp + 4);
        bf16x8 v8;
        v8[0] = f2b(f0.x); v8[1] = f2b(f0.y); v8[2] = f2b(f0.z); v8[3] = f2b(f0.w);
        v8[4] = f2b(f1.x); v8[5] = f2b(f1.y); v8[6] = f2b(f1.z); v8[7] = f2b(f1.w);
        *(bf16x8*)&trk[swz(row, gg)] = v8;
    }

    #pragma unroll
    for (int sl = 0; sl < SN; ++sl) {
        const float wx = cxa[sl] - (float)fx, wy = cya[sl] - (float)fy;
        const float w00 = (1.f - wx) * (1.f - wy), w10 = wx * (1.f - wy);
        const float w01 = (1.f - wx) * wy,         w11 = wx * wy;
        const int offs = (fx - 3 - e) * 66;

        asm volatile("s_waitcnt vmcnt(0)" ::: "memory");
        __syncthreads();   // patch landed; prev bilinear readers of pcL done

        // ---- MFMA: pc[80][64] = patch(80x128) . trk(64x128)^T -> pcL bf16 --
        {
            f32x4 acc[5] = {};
            #pragma unroll
            for (int kk = 0; kk < 4; ++kk) {
                int gg = kk * 4 + kq;
                bf16x8 b = *(const bf16x8*)&trk[swz(wv * 16 + rsub, gg)];
                #pragma unroll
                for (int ti = 0; ti < 5; ++ti) {
                    bf16x8 a = *(const bf16x8*)&patch[swz(ti * 16 + rsub, gg)];
                    acc[ti] = __builtin_amdgcn_mfma_f32_16x16x32_bf16(a, b, acc[ti], 0, 0, 0);
                }
            }
            const int col = wv * 16 + rsub;   // ij dim, 0..63 (<66 stride: safe)
            #pragma unroll
            for (int ti = 0; ti < 5; ++ti)
                #pragma unroll
                for (int r = 0; r < 4; ++r)
                    pcL[(ti * 16 + kq * 4 + r) * 66 + col] = f2b(acc[ti][r]);
        }
        __syncthreads();   // pcL ready; patch consumed

        // ---- issue next-s patch loads (overlap with bilinear) ----
        if (sl + 1 < SN) {
            fx = (int)floorf(cxa[sl + 1]); fy = (int)floorf(cya[sl + 1]);
            e = (fx - 3) & ~1;
            const unsigned short* base =
                fpad + (size_t)(sl + 1) * plane + ((fy + 1) * Wp + (e + 4)) * CC;
            #pragma unroll
            for (int i = 0; i < 5; ++i) gll16(base + poff[i], &patch[ldso[i]]);
        }

        // ---- bilinear on output domain; packed b32 coalesced stores ----
        {
            unsigned* vrow32 = (unsigned*)(vol + ((size_t)(g * SN + sl) * NN + n) * K1P);
            #pragma unroll
            for (int i = 0; i < 5; ++i) {
                int d = t + i * 256;
                if (d < K1P / 2) {
                    unsigned lo = 0, hi = 0;
                    if (lutA[i] != 0xFFFFFFFFu) {
                        int idx = (int)lutA[i] + offs;
                        float v = w00 * b2f(pcL[idx])       + w10 * b2f(pcL[idx + 66])
                                + w01 * b2f(pcL[idx + 660]) + w11 * b2f(pcL[idx + 726]);
                        lo = f2b(v);
                    }
                    if (lutB[i] != 0xFFFFFFFFu) {
                        int idx = (int)lutB[i] + offs;
                        float v = w00 * b2f(pcL[idx])       + w10 * b2f(pcL[idx + 66])
                                + w01 * b2f(pcL[idx + 660]) + w11 * b2f(pcL[idx + 726]);
                        hi = f2b(v);
                    }
                    vrow32[d] = lo | (hi << 16);
                }
            }
        }
    }
}

// ---------------------------------------------------------------------------
// GEMM1: H = gelu(vol @ w1 + b1).  (rows x 2432) @ (2432 x 384) bf16.
// 4-buffer counted-vmcnt pipeline: prologue stages 4 tiles; per iter
// vmcnt(12|8|4|0) -> barrier -> ds_read+MFMA -> barrier -> restage st+4.
// ---------------------------------------------------------------------------
__global__ __launch_bounds__(256, 2) void gemm1_kernel(
    const unsigned short* __restrict__ A,   // rows x 2432
    const unsigned short* __restrict__ Bt,  // 384 x 2432 (= w1^T)
    const float* __restrict__ bias,
    unsigned short* __restrict__ Hout)      // rows x 384
{
    __shared__ __align__(16) unsigned short As[4 * 128 * 32];
    __shared__ __align__(16) unsigned short Bs[4 * 128 * 32];
    const int h = blockIdx.x, q = gridDim.x >> 3;
    const int l = (h & 7) * q + (h >> 3);
    const int m0 = (l / 3) * 128, n0 = (l % 3) * 128;
    const int t = threadIdx.x, lane = t & 63, wv = t >> 6;
    const int wm = wv >> 1, wn = wv & 1;
    const int rsub = lane & 15, kq = lane >> 4;

    const int rA0 = t >> 2, sA0 = (t & 3) ^ ((rA0 >> 1) & 3);
    const int rA1 = (t + 256) >> 2, sA1 = ((t + 256) & 3) ^ ((rA1 >> 1) & 3);
    const unsigned short* gA0 = A  + (size_t)(m0 + rA0) * K1P + sA0 * 8;
    const unsigned short* gA1 = A  + (size_t)(m0 + rA1) * K1P + sA1 * 8;
    const unsigned short* gB0 = Bt + (size_t)(n0 + rA0) * K1P + sA0 * 8;
    const unsigned short* gB1 = Bt + (size_t)(n0 + rA1) * K1P + sA1 * 8;
    const int chunk0 = (t & ~63) * 8, chunk1 = (256 + (t & ~63)) * 8;

    f32x4 acc[4][4] = {};

    const int NSTEP = K1P / 32;  // 76
    #pragma unroll
    for (int p = 0; p < 4; ++p) {
        size_t ko = (size_t)p * 32;
        int lb = p * 4096;
        gll16(gA0 + ko, &As[lb + chunk0]); gll16(gA1 + ko, &As[lb + chunk1]);
        gll16(gB0 + ko, &Bs[lb + chunk0]); gll16(gB1 + ko, &Bs[lb + chunk1]);
    }
    int cur = 0;
    for (int st = 0; st < NSTEP; ++st) {
        const int rem = NSTEP - 1 - st;
        if (rem >= 3)      asm volatile("s_waitcnt vmcnt(12)" ::: "memory");
        else if (rem == 2) asm volatile("s_waitcnt vmcnt(8)" ::: "memory");
        else if (rem == 1) asm volatile("s_waitcnt vmcnt(4)" ::: "memory");
        else               asm volatile("s_waitcnt vmcnt(0)" ::: "memory");
        __builtin_amdgcn_s_barrier();
        __builtin_amdgcn_sched_barrier(0);
        const int lb = cur * 4096;
        bf16x8 af[4], bfr[4];
        #pragma unroll
        for (int mi = 0; mi < 4; ++mi) {
            int r = wm * 64 + mi * 16 + rsub;
            int phys = r * 4 + (kq ^ ((r >> 1) & 3));
            af[mi] = *(const bf16x8*)&As[lb + phys * 8];
        }
        #pragma unroll
        for (int ni = 0; ni < 4; ++ni) {
            int r = wn * 64 + ni * 16 + rsub;
            int phys = r * 4 + (kq ^ ((r >> 1) & 3));
            bfr[ni] = *(const bf16x8*)&Bs[lb + phys * 8];
        }
        #pragma unroll
        for (int mi = 0; mi < 4; ++mi)
            #pragma unroll
            for (int ni = 0; ni < 4; ++ni)
                acc[mi][ni] = __builtin_amdgcn_mfma_f32_16x16x32_bf16(
                    af[mi], bfr[ni], acc[mi][ni], 0, 0, 0);
        __builtin_amdgcn_sched_barrier(0);
        __builtin_amdgcn_s_barrier();
        __builtin_amdgcn_sched_barrier(0);
        if (st + 4 < NSTEP) {
            size_t ko = (size_t)(st + 4) * 32;
            gll16(gA0 + ko, &As[lb + chunk0]);
            gll16(gA1 + ko, &As[lb + chunk1]);
            gll16(gB0 + ko, &Bs[lb + chunk0]);
            gll16(gB1 + ko, &Bs[lb + chunk1]);
        }
        cur = (cur + 1) & 3;
    }
    #pragma unroll
    for (int mi = 0; mi < 4; ++mi) {
        int row = m0 + wm * 64 + mi * 16 + kq * 4;
        #pragma unroll
        for (int ni = 0; ni < 4; ++ni) {
            int col = n0 + wn * 64 + ni * 16 + rsub;
            float bcol = bias[col];
            #pragma unroll
            for (int r = 0; r < 4; ++r) {
                float x = acc[mi][ni][r] + bcol;
                float gg = 0.5f * x * (1.f + erff(x * 0.70710678118654752f));
                Hout[(size_t)(row + r) * H1 + col] = f2b(gg);
            }
        }
    }
}

// ---------------------------------------------------------------------------
// GEMM2: out slice = H @ w2 + b2 + time_emb.  (rows x 384) @ (384 x 256).
// Same 4-buffer pipeline. Rows span fused levels.
// ---------------------------------------------------------------------------
__global__ __launch_bounds__(256, 2) void gemm2_kernel(
    const unsigned short* __restrict__ A,   // rows x 384
    const unsigned short* __restrict__ Bt,  // 256 x 384 (= w2^T)
    const float* __restrict__ bias,
    const float* __restrict__ te,           // (8, 1110)
    float* __restrict__ out,                // (N, 8, 1110)
    int lv0)
{
    __shared__ __align__(16) unsigned short As[4 * 128 * 32];
    __shared__ __align__(16) unsigned short Bs[4 * 128 * 32];
    const int h = blockIdx.x, q = gridDim.x >> 3;
    const int l = (h & 7) * q + (h >> 3);
    const int m0 = (l >> 1) * 128, n0 = (l & 1) * 128;
    const int t = threadIdx.x, lane = t & 63, wv = t >> 6;
    const int wm = wv >> 1, wn = wv & 1;
    const int rsub = lane & 15, kq = lane >> 4;

    const int rA0 = t >> 2, sA0 = (t & 3) ^ ((rA0 >> 1) & 3);
    const int rA1 = (t + 256) >> 2, sA1 = ((t + 256) & 3) ^ ((rA1 >> 1) & 3);
    const unsigned short* gA0 = A  + (size_t)(m0 + rA0) * H1 + sA0 * 8;
    const unsigned short* gA1 = A  + (size_t)(m0 + rA1) * H1 + sA1 * 8;
    const unsigned short* gB0 = Bt + (size_t)(n0 + rA0) * H1 + sA0 * 8;
    const unsigned short* gB1 = Bt + (size_t)(n0 + rA1) * H1 + sA1 * 8;
    const int chunk0 = (t & ~63) * 8, chunk1 = (256 + (t & ~63)) * 8;

    f32x4 acc[4][4] = {};

    const int NSTEP = H1 / 32;  // 12
    #pragma unroll
    for (int p = 0; p < 4; ++p) {
        size_t ko = (size_t)p * 32;
        int lb = p * 4096;
        gll16(gA0 + ko, &As[lb + chunk0]); gll16(gA1 + ko, &As[lb + chunk1]);
        gll16(gB0 + ko, &Bs[lb + chunk0]); gll16(gB1 + ko, &Bs[lb + chunk1]);
    }
    int cur = 0;
    for (int st = 0; st < NSTEP; ++st) {
        const int rem = NSTEP - 1 - st;
        if (rem >= 3)      asm volatile("s_waitcnt vmcnt(12)" ::: "memory");
        else if (rem == 2) asm volatile("s_waitcnt vmcnt(8)" ::: "memory");
        else if (rem == 1) asm volatile("s_waitcnt vmcnt(4)" ::: "memory");
        else               asm volatile("s_waitcnt vmcnt(0)" ::: "memory");
        __builtin_amdgcn_s_barrier();
        __builtin_amdgcn_sched_barrier(0);
        const int lb = cur * 4096;
        bf16x8 af[4], bfr[4];
        #pragma unroll
        for (int mi = 0; mi < 4; ++mi) {
            int r = wm * 64 + mi * 16 + rsub;
            int phys = r * 4 + (kq ^ ((r >> 1) & 3));
            af[mi] = *(const bf16x8*)&As[lb + phys * 8];
        }
        #pragma unroll
        for (int ni = 0; ni < 4; ++ni) {
            int r = wn * 64 + ni * 16 + rsub;
            int phys = r * 4 + (kq ^ ((r >> 1) & 3));
            bfr[ni] = *(const bf16x8*)&Bs[lb + phys * 8];
        }
        #pragma unroll
        for (int mi = 0; mi < 4; ++mi)
            #pragma unroll
            for (int ni = 0; ni < 4; ++ni)
                acc[mi][ni] = __builtin_amdgcn_mfma_f32_16x16x32_bf16(
                    af[mi], bfr[ni], acc[mi][ni], 0, 0, 0);
        __builtin_amdgcn_sched_barrier(0);
        __builtin_amdgcn_s_barrier();
        __builtin_amdgcn_sched_barrier(0);
        if (st + 4 < NSTEP) {
            size_t ko = (size_t)(st + 4) * 32;
            gll16(gA0 + ko, &As[lb + chunk0]);
            gll16(gA1 + ko, &As[lb + chunk1]);
            gll16(gB0 + ko, &Bs[lb + chunk0]);
            gll16(gB1 + ko, &Bs[lb + chunk1]);
        }
        cur = (cur + 1) & 3;
    }
    #pragma unroll
    for (int mi = 0; mi < 4; ++mi) {
        int rowb = m0 + wm * 64 + mi * 16 + kq * 4;
        #pragma unroll
        for (int ni = 0; ni < 4; ++ni) {
            int col = n0 + wn * 64 + ni * 16 + rsub;
            float bcol = bias[col];
            #pragma unroll
            for (int r = 0; r < 4; ++r) {
                int row = rowb + r;
                int g = row >> 13, s = (row >> 10) & 7, n = row & 1023;
                int dcol = 2 + (lv0 + g) * H2 + col;
                out[((size_t)n * SN + s) * DOUT + dcol] =
                    acc[mi][ni][r] + bcol + te[s * DOUT + dcol];
            }
        }
    }
}

// ---------------------------------------------------------------------------
// Transpose + bf16-convert: in (K x Nw f32) -> out (Nw x Kp bf16), zero-pad.
// ---------------------------------------------------------------------------
__global__ __launch_bounds__(256) void conv_t_kernel(
    const float* __restrict__ in, unsigned short* __restrict__ outp,
    int K, int Nw, int Kp)
{
    __shared__ float tile[32][33];
    const int kb = blockIdx.x * 32, nb = blockIdx.y * 32;
    const int tx = threadIdx.x & 31, ty = threadIdx.x >> 5;
    #pragma unroll
    for (int i = 0; i < 32; i += 8) {
        int k = kb + ty + i, nn = nb + tx;
        tile[ty + i][tx] = (k < K && nn < Nw) ? in[(size_t)k * Nw + nn] : 0.f;
    }
    __syncthreads();
    #pragma unroll
    for (int i = 0; i < 32; i += 8) {
        int nn = nb + ty + i, k = kb + tx;
        if (nn < Nw) outp[(size_t)nn * Kp + k] = f2b(tile[tx][ty + i]);
    }
}

// Kernel D: vis, conf, rel_emb(84) + time_emb.
__global__ __launch_bounds__(128) void tail_kernel(
    const float* __restrict__ coords, const float* __restrict__ vis,
    const float* __restrict__ conf, const float* __restrict__ te,
    float* __restrict__ out)
{
    const int b = blockIdx.x;
    const int n = b >> 3, s = b & 7;
    const int d = threadIdx.x;
    if (d >= 86) return;
    const size_t ob = (size_t)b * DOUT;
    if (d == 0) {
        out[ob + 0] = vis[(size_t)s * NN + n] + te[s * DOUT + 0];
    } else if (d == 1) {
        out[ob + 1] = conf[(size_t)s * NN + n] + te[s * DOUT + 1];
    } else {
        int rd = d - 2;
        float cx = coords[((size_t)s * NN + n) * 2 + 0];
        float cy = coords[((size_t)s * NN + n) * 2 + 1];
        float rfx = 0.f, rfy = 0.f, rbx = 0.f, rby = 0.f;
        if (s < SN - 1) {
            rfx = cx - coords[((size_t)(s + 1) * NN + n) * 2 + 0];
            rfy = cy - coords[((size_t)(s + 1) * NN + n) * 2 + 1];
        }
        if (s > 0) {
            rbx = cx - coords[((size_t)(s - 1) * NN + n) * 2 + 0];
            rby = cy - coords[((size_t)(s - 1) * NN + n) * 2 + 1];
        }
        float r4[4] = {rfx / 128.f, rfy / 96.f, rbx / 128.f, rby / 96.f};
        float val;
        if (rd < 4) {
            val = r4[rd];
        } else if (rd < 44) {
            int q = rd - 4; int deg = q >> 2, comp = q & 3;
            val = sinf(r4[comp] * (float)(1 << deg));
        } else {
            int q = rd - 44; int deg = q >> 2, comp = q & 3;
            val = sinf(r4[comp] * (float)(1 << deg) + 1.57079632679489662f);
        }
        int od = 1026 + rd;
        out[ob + od] = val + te[s * DOUT + od];
    }
}

extern "C" void kernel_launch(void* const* d_in, const int* in_sizes, int n_in,
                              void* d_out, int out_size, void* d_ws, size_t ws_size,
                              hipStream_t stream) {
    const float* fmaps[4] = {(const float*)d_in[0], (const float*)d_in[2],
                             (const float*)d_in[4], (const float*)d_in[6]};
    const float* track[4] = {(const float*)d_in[1], (const float*)d_in[3],
                             (const float*)d_in[5], (const float*)d_in[7]};
    const float* coords = (const float*)d_in[8];
    const float* vis    = (const float*)d_in[9];
    const float* conf   = (const float*)d_in[10];
    const float* w1     = (const float*)d_in[11];
    const float* b1     = (const float*)d_in[12];
    const float* w2     = (const float*)d_in[13];
    const float* b2     = (const float*)d_in[14];
    const float* te     = (const float*)d_in[15];
    float* out = (float*)d_out;

    const int Hs[4] = {96, 48, 24, 12};
    const int Ws[4] = {128, 64, 32, 16};

    // ---- workspace layout ----
    char* wsb = (char*)d_ws;
    unsigned short* w1t = (unsigned short*)wsb;
    size_t off = (size_t)H1 * K1P * 2;
    unsigned short* w2t = (unsigned short*)(wsb + off);
    off += (size_t)H2 * H1 * 2;
    unsigned short* fpad[4];
    for (int l = 0; l < 4; ++l) {
        fpad[l] = (unsigned short*)(wsb + off);
        off += (size_t)SN * (Hs[l] + 8) * (Ws[l] + 8) * CC * 2;
    }
    off += 512;  // slack
    const size_t fixed = off;
    int n_lv = 4;
    while (n_lv > 1 &&
           fixed + (size_t)n_lv * SN * NN * (K1P + H1) * 2 > ws_size)
        n_lv >>= 1;
    unsigned short* volb = (unsigned short*)(wsb + fixed);
    unsigned short* hb   = volb + (size_t)n_lv * SN * NN * K1P;

    // ---- weight prep + fmap conversion ----
    conv_t_kernel<<<dim3(K1P / 32, H1 / 32), 256, 0, stream>>>(w1, w1t, 2401, H1, K1P);
    conv_t_kernel<<<dim3(H1 / 32, H2 / 32), 256, 0, stream>>>(w2, w2t, H1, H2, H1);
    for (int l = 0; l < 4; ++l)
        conv_fmap_kernel<<<SN * (Hs[l] + 8), 256, 0, stream>>>(
            fmaps[l], fpad[l], Hs[l], Ws[l]);

    for (int lv0 = 0; lv0 < 4; lv0 += n_lv) {
        sample_vol_kernel<<<n_lv * NN, 256, 0, stream>>>(
            fpad[0], fpad[1], fpad[2], fpad[3],
            track[0], track[1], track[2], track[3],
            coords, volb, lv0);
        const int rows = n_lv * SN * NN;
        gemm1_kernel<<<(rows / 128) * 3, 256, 0, stream>>>(volb, w1t, b1, hb);
        gemm2_kernel<<<(rows / 128) * 2, 256, 0, stream>>>(hb, w2t, b2, te, out, lv0);
    }
    tail_kernel<<<SN * NN, 128, 0, stream>>>(coords, vis, conf, te, out);
}

// Round 11
// 344.604 us; speedup vs baseline: 1.4851x; 1.1248x over previous
//
#include <hip/hip_runtime.h>
#include <math.h>

// ---------------------------------------------------------------------------
// CoTracker correlation-embedding pipeline, bf16 MFMA, HWC-padded fmaps.
// Round 10: gemm1/gemm2 reverted to validated R5 3-buffer (3 blocks/CU).
// sample_vol: R5 structure with counted-vmcnt raw barriers (no store drains).
// Inputs: 0:fmaps0 1:track0 2:fmaps1 3:track1 4:fmaps2 5:track2 6:fmaps3
//         7:track3 8:coords 9:vis 10:conf 11:w1 12:b1 13:w2 14:b2 15:time_emb
// Output: (1,N,8,1110) f32.
// ---------------------------------------------------------------------------

#define SN 8
#define NN 1024
#define CC 128
#define K1P 2432
#define H1 384
#define H2 256
#define DOUT 1110

typedef short bf16x8 __attribute__((ext_vector_type(8)));
typedef float f32x4 __attribute__((ext_vector_type(4)));

__device__ inline unsigned short f2b(float x) {  // RTNE f32 -> bf16
    union { float f; unsigned u; } v; v.f = x;
    unsigned r = v.u + 0x7FFFu + ((v.u >> 16) & 1u);
    return (unsigned short)(r >> 16);
}
__device__ inline float b2f(unsigned short u) {
    union { unsigned u; float f; } v; v.u = (unsigned)u << 16; return v.f;
}
__device__ inline void gll16(const void* g, void* l) {
    __builtin_amdgcn_global_load_lds(
        (const __attribute__((address_space(1))) void*)g,
        (__attribute__((address_space(3))) void*)l, 16, 0, 0);
}
// XOR-swizzled LDS index (shorts) for [rows][128] bf16 MFMA operand tiles.
__device__ inline int swz(int row, int g) {
    return row * 128 + ((g ^ (row & 7)) << 3);
}

// ---------------------------------------------------------------------------
// fmap fp32 (S,C,H,W) -> bf16 HWC padded (S, H+8, W+8, C), border replicate.
// ---------------------------------------------------------------------------
__global__ __launch_bounds__(256) void conv_fmap_kernel(
    const float* __restrict__ in, unsigned short* __restrict__ outp,
    int H, int W)
{
    const int Hp = H + 8, Wp = W + 8;
    const int s = blockIdx.x / Hp, yp = blockIdx.x % Hp;
    const int y = min(max(yp - 4, 0), H - 1);
    const float* src = in + (size_t)s * CC * H * W + (size_t)y * W;
    unsigned short* dst = outp + ((size_t)s * Hp + yp) * Wp * CC;
    for (int idx = threadIdx.x; idx < Wp * CC; idx += 256) {
        int xp = idx >> 7, c = idx & 127;
        int x = min(max(xp - 4, 0), W - 1);
        dst[idx] = f2b(src[(size_t)c * H * W + x]);
    }
}

// ---------------------------------------------------------------------------
// Kernel A (fused over levels): block -> (g = blk>>10, n = blk&1023).
// trk loaded once (swizzled). Per s (fully unrolled):
//   [counted vmcnt + raw bar] MFMA pc[80][64] -> pcL bf16 [80][66]
//   [lgkm bar] prefetch next patch -> bilinear (register LUT) -> packed b32.
// LDS ~46.3KB -> 3 blocks/CU.
// ---------------------------------------------------------------------------
__global__ __launch_bounds__(256, 3) void sample_vol_kernel(
    const unsigned short* __restrict__ fq0, const unsigned short* __restrict__ fq1,
    const unsigned short* __restrict__ fq2, const unsigned short* __restrict__ fq3,
    const float* __restrict__ tk0, const float* __restrict__ tk1,
    const float* __restrict__ tk2, const float* __restrict__ tk3,
    const float* __restrict__ coords,        // (8, N, 2) f32
    unsigned short* __restrict__ vol,        // (n_lv*8*N, 2432) bf16
    int lv0)
{
    __shared__ __align__(16) unsigned short patch[80 * 128]; // 20 KB
    __shared__ __align__(16) unsigned short trk[64 * 128];   // 16 KB
    __shared__ __align__(16) unsigned short pcL[80 * 66];    // 10.3 KB
    const int n = blockIdx.x & 1023, g = blockIdx.x >> 10;
    const int lvl = lv0 + g;
    const unsigned short* fpad = (lvl == 0) ? fq0 : (lvl == 1) ? fq1
                               : (lvl == 2) ? fq2 : fq3;
    const float* track = (lvl == 0) ? tk0 : (lvl == 1) ? tk1
                       : (lvl == 2) ? tk2 : tk3;
    const int Wp = (128 >> lvl) + 8;
    const int t = threadIdx.x;
    const int lane = t & 63, wv = t >> 6;
    const int rsub = lane & 15, kq = lane >> 4;
    const float inv = 1.0f / (float)(1 << lvl);
    const size_t plane = (size_t)((96 >> lvl) + 8) * Wp * CC;

    // per-lane static patch-load offsets (pre-swizzled global granule)
    int poff[5], ldso[5];
    #pragma unroll
    for (int i = 0; i < 5; ++i) {
        int task64 = wv * 5 + i;
        int point = task64 * 4 + (lane >> 4);  // patch row 0..79
        int v = point / 10, xs = point - v * 10;
        int j = (lane & 15) ^ (point & 7);
        poff[i] = (v * Wp + xs) * CC + j * 8;
        ldso[i] = task64 * 512;
    }

    // hoist all 8 coords into registers
    float cxa[SN], cya[SN];
    #pragma unroll
    for (int s = 0; s < SN; ++s) {
        float2 c2 = *(const float2*)&coords[((size_t)s * NN + n) * 2];
        cxa[s] = c2.x * inv; cya[s] = c2.y * inv;
    }

    // register LUT for bilinear output decomposition (divs once per thread)
    unsigned lutA[5], lutB[5];
    #pragma unroll
    for (int i = 0; i < 5; ++i) {
        int d = t + i * 256;
        int o0 = 2 * d, o1 = 2 * d + 1;
        lutA[i] = 0xFFFFFFFFu; lutB[i] = 0xFFFFFFFFu;
        if (o0 < 2401) {
            int ab = o0 / 49, ij = o0 - 49 * ab, a = ab / 7, b = ab - 7 * a;
            lutA[i] = (unsigned)((b * 10 + a) * 66 + ij);
        }
        if (o1 < 2401) {
            int ab = o1 / 49, ij = o1 - 49 * ab, a = ab / 7, b = ab - 7 * a;
            lutB[i] = (unsigned)((b * 10 + a) * 66 + ij);
        }
    }

    // first patch issue (these 5 loads stay the OLDEST VMEM entries)
    int fx = (int)floorf(cxa[0]), fy = (int)floorf(cya[0]);
    int e = (fx - 3) & ~1;
    {
        const unsigned short* base = fpad + ((fy + 1) * Wp + (e + 4)) * CC;
        #pragma unroll
        for (int i = 0; i < 5; ++i) gll16(base + poff[i], &patch[ldso[i]]);
    }
    // track[n] -> trk LDS (swizzled), once
    for (int task = t; task < 49 * 16; task += 256) {
        int row = task >> 4, gg = task & 15;
        const float* srcp = &track[((size_t)row * NN + n) * CC + gg * 8];
        float4 f0 = *(const float4*)srcp;
        float4 f1 = *(const float4*)(srcp + 4);
        bf16x8 v8;
        v8[0] = f2b(f0.x); v8[1] = f2b(f0.y); v8[2] = f2b(f0.z); v8[3] = f2b(f0.w);
        v8[4] = f2b(f1.x); v8[5] = f2b(f1.y); v8[6] = f2b(f1.z); v8[7] = f2b(f1.w);
        *(bf16x8*)&trk[swz(row, gg)] = v8;
    }

    #pragma unroll
    for (int sl = 0; sl < SN; ++sl) {
        const float wx = cxa[sl] - (float)fx, wy = cya[sl] - (float)fy;
        const float w00 = (1.f - wx) * (1.f - wy), w10 = wx * (1.f - wy);
        const float w01 = (1.f - wx) * wy,         w11 = wx * wy;
        const int offs = (fx - 3 - e) * 66;

        // top barrier: patch loads landed. Loads are the 5 OLDEST VMEM ops;
        // newer entries are this wave's bilinear stores from iter sl-1
        // (5 for waves 0-2, 4 for wave 3 due to the d<1216 guard) -> counted
        // wait skips the store drain. sl==0: full drain (prologue loads).
        if (sl == 0)      asm volatile("s_waitcnt vmcnt(0) lgkmcnt(0)" ::: "memory");
        else if (wv == 3) asm volatile("s_waitcnt vmcnt(4) lgkmcnt(0)" ::: "memory");
        else              asm volatile("s_waitcnt vmcnt(5) lgkmcnt(0)" ::: "memory");
        __builtin_amdgcn_sched_barrier(0);
        __builtin_amdgcn_s_barrier();
        __builtin_amdgcn_sched_barrier(0);

        // ---- MFMA: pc[80][64] = patch(80x128) . trk(64x128)^T -> pcL bf16 --
        {
            f32x4 acc[5] = {};
            #pragma unroll
            for (int kk = 0; kk < 4; ++kk) {
                int gg = kk * 4 + kq;
                bf16x8 b = *(const bf16x8*)&trk[swz(wv * 16 + rsub, gg)];
                #pragma unroll
                for (int ti = 0; ti < 5; ++ti) {
                    bf16x8 a = *(const bf16x8*)&patch[swz(ti * 16 + rsub, gg)];
                    acc[ti] = __builtin_amdgcn_mfma_f32_16x16x32_bf16(a, b, acc[ti], 0, 0, 0);
                }
            }
            const int col = wv * 16 + rsub;   // ij dim, 0..63 (<66 stride: safe)
            #pragma unroll
            for (int ti = 0; ti < 5; ++ti)
                #pragma unroll
                for (int r = 0; r < 4; ++r)
                    pcL[(ti * 16 + kq * 4 + r) * 66 + col] = f2b(acc[ti][r]);
        }
        // mid barrier: pcL visible; patch consumed (MFMA reads retired via
        // lgkm data-dependency). LGKM-only wait: stores stay in flight.
        asm volatile("s_waitcnt lgkmcnt(0)" ::: "memory");
        __builtin_amdgcn_s_barrier();
        __builtin_amdgcn_sched_barrier(0);

        // ---- issue next-s patch loads FIRST (oldest in queue) ----
        if (sl + 1 < SN) {
            fx = (int)floorf(cxa[sl + 1]); fy = (int)floorf(cya[sl + 1]);
            e = (fx - 3) & ~1;
            const unsigned short* base =
                fpad + (size_t)(sl + 1) * plane + ((fy + 1) * Wp + (e + 4)) * CC;
            #pragma unroll
            for (int i = 0; i < 5; ++i) gll16(base + poff[i], &patch[ldso[i]]);
        }
        __builtin_amdgcn_sched_barrier(0);

        // ---- bilinear on output domain; packed b32 coalesced stores ----
        {
            unsigned* vrow32 = (unsigned*)(vol + ((size_t)(g * SN + sl) * NN + n) * K1P);
            #pragma unroll
            for (int i = 0; i < 5; ++i) {
                int d = t + i * 256;
                if (d < K1P / 2) {
                    unsigned lo = 0, hi = 0;
                    if (lutA[i] != 0xFFFFFFFFu) {
                        int idx = (int)lutA[i] + offs;
                        float v = w00 * b2f(pcL[idx])       + w10 * b2f(pcL[idx + 66])
                                + w01 * b2f(pcL[idx + 660]) + w11 * b2f(pcL[idx + 726]);
                        lo = f2b(v);
                    }
                    if (lutB[i] != 0xFFFFFFFFu) {
                        int idx = (int)lutB[i] + offs;
                        float v = w00 * b2f(pcL[idx])       + w10 * b2f(pcL[idx + 66])
                                + w01 * b2f(pcL[idx + 660]) + w11 * b2f(pcL[idx + 726]);
                        hi = f2b(v);
                    }
                    vrow32[d] = lo | (hi << 16);
                }
            }
        }
    }
}

// ---------------------------------------------------------------------------
// GEMM1: H = gelu(vol @ w1 + b1).  (rows x 2432) @ (2432 x 384) bf16.
// 3-buffer counted-vmcnt pipeline (validated R5 config).
// ---------------------------------------------------------------------------
__global__ __launch_bounds__(256, 3) void gemm1_kernel(
    const unsigned short* __restrict__ A,   // rows x 2432
    const unsigned short* __restrict__ Bt,  // 384 x 2432 (= w1^T)
    const float* __restrict__ bias,
    unsigned short* __restrict__ Hout)      // rows x 384
{
    __shared__ __align__(16) unsigned short As[3 * 128 * 32];
    __shared__ __align__(16) unsigned short Bs[3 * 128 * 32];
    const int h = blockIdx.x, q = gridDim.x >> 3;
    const int l = (h & 7) * q + (h >> 3);
    const int m0 = (l / 3) * 128, n0 = (l % 3) * 128;
    const int t = threadIdx.x, lane = t & 63, wv = t >> 6;
    const int wm = wv >> 1, wn = wv & 1;
    const int rsub = lane & 15, kq = lane >> 4;

    const int rA0 = t >> 2, sA0 = (t & 3) ^ ((rA0 >> 1) & 3);
    const int rA1 = (t + 256) >> 2, sA1 = ((t + 256) & 3) ^ ((rA1 >> 1) & 3);
    const unsigned short* gA0 = A  + (size_t)(m0 + rA0) * K1P + sA0 * 8;
    const unsigned short* gA1 = A  + (size_t)(m0 + rA1) * K1P + sA1 * 8;
    const unsigned short* gB0 = Bt + (size_t)(n0 + rA0) * K1P + sA0 * 8;
    const unsigned short* gB1 = Bt + (size_t)(n0 + rA1) * K1P + sA1 * 8;
    const int chunk0 = (t & ~63) * 8, chunk1 = (256 + (t & ~63)) * 8;

    f32x4 acc[4][4] = {};

    const int NSTEP = K1P / 32;  // 76
    #pragma unroll
    for (int p = 0; p < 3; ++p) {
        size_t ko = (size_t)p * 32;
        int lb = p * 4096;
        gll16(gA0 + ko, &As[lb + chunk0]); gll16(gA1 + ko, &As[lb + chunk1]);
        gll16(gB0 + ko, &Bs[lb + chunk0]); gll16(gB1 + ko, &Bs[lb + chunk1]);
    }
    int cur = 0;
    for (int st = 0; st < NSTEP; ++st) {
        const int rem = NSTEP - 1 - st;
        if (rem >= 2)      asm volatile("s_waitcnt vmcnt(8)" ::: "memory");
        else if (rem == 1) asm volatile("s_waitcnt vmcnt(4)" ::: "memory");
        else               asm volatile("s_waitcnt vmcnt(0)" ::: "memory");
        __builtin_amdgcn_s_barrier();
        __builtin_amdgcn_sched_barrier(0);
        const int lb = cur * 4096;
        bf16x8 af[4], bfr[4];
        #pragma unroll
        for (int mi = 0; mi < 4; ++mi) {
            int r = wm * 64 + mi * 16 + rsub;
            int phys = r * 4 + (kq ^ ((r >> 1) & 3));
            af[mi] = *(const bf16x8*)&As[lb + phys * 8];
        }
        #pragma unroll
        for (int ni = 0; ni < 4; ++ni) {
            int r = wn * 64 + ni * 16 + rsub;
            int phys = r * 4 + (kq ^ ((r >> 1) & 3));
            bfr[ni] = *(const bf16x8*)&Bs[lb + phys * 8];
        }
        #pragma unroll
        for (int mi = 0; mi < 4; ++mi)
            #pragma unroll
            for (int ni = 0; ni < 4; ++ni)
                acc[mi][ni] = __builtin_amdgcn_mfma_f32_16x16x32_bf16(
                    af[mi], bfr[ni], acc[mi][ni], 0, 0, 0);
        __builtin_amdgcn_sched_barrier(0);
        __builtin_amdgcn_s_barrier();
        __builtin_amdgcn_sched_barrier(0);
        if (st + 3 < NSTEP) {
            size_t ko = (size_t)(st + 3) * 32;
            gll16(gA0 + ko, &As[lb + chunk0]);
            gll16(gA1 + ko, &As[lb + chunk1]);
            gll16(gB0 + ko, &Bs[lb + chunk0]);
            gll16(gB1 + ko, &Bs[lb + chunk1]);
        }
        cur = (cur == 2) ? 0 : cur + 1;
    }
    #pragma unroll
    for (int mi = 0; mi < 4; ++mi) {
        int row = m0 + wm * 64 + mi * 16 + kq * 4;
        #pragma unroll
        for (int ni = 0; ni < 4; ++ni) {
            int col = n0 + wn * 64 + ni * 16 + rsub;
            float bcol = bias[col];
            #pragma unroll
            for (int r = 0; r < 4; ++r) {
                float x = acc[mi][ni][r] + bcol;
                float gg = 0.5f * x * (1.f + erff(x * 0.70710678118654752f));
                Hout[(size_t)(row + r) * H1 + col] = f2b(gg);
            }
        }
    }
}

// ---------------------------------------------------------------------------
// GEMM2: out slice = H @ w2 + b2 + time_emb.  (rows x 384) @ (384 x 256).
// ---------------------------------------------------------------------------
__global__ __launch_bounds__(256, 3) void gemm2_kernel(
    const unsigned short* __restrict__ A,   // rows x 384
    const unsigned short* __restrict__ Bt,  // 256 x 384 (= w2^T)
    const float* __restrict__ bias,
    const float* __restrict__ te,           // (8, 1110)
    float* __restrict__ out,                // (N, 8, 1110)
    int lv0)
{
    __shared__ __align__(16) unsigned short As[3 * 128 * 32];
    __shared__ __align__(16) unsigned short Bs[3 * 128 * 32];
    const int h = blockIdx.x, q = gridDim.x >> 3;
    const int l = (h & 7) * q + (h >> 3);
    const int m0 = (l >> 1) * 128, n0 = (l & 1) * 128;
    const int t = threadIdx.x, lane = t & 63, wv = t >> 6;
    const int wm = wv >> 1, wn = wv & 1;
    const int rsub = lane & 15, kq = lane >> 4;

    const int rA0 = t >> 2, sA0 = (t & 3) ^ ((rA0 >> 1) & 3);
    const int rA1 = (t + 256) >> 2, sA1 = ((t + 256) & 3) ^ ((rA1 >> 1) & 3);
    const unsigned short* gA0 = A  + (size_t)(m0 + rA0) * H1 + sA0 * 8;
    const unsigned short* gA1 = A  + (size_t)(m0 + rA1) * H1 + sA1 * 8;
    const unsigned short* gB0 = Bt + (size_t)(n0 + rA0) * H1 + sA0 * 8;
    const unsigned short* gB1 = Bt + (size_t)(n0 + rA1) * H1 + sA1 * 8;
    const int chunk0 = (t & ~63) * 8, chunk1 = (256 + (t & ~63)) * 8;

    f32x4 acc[4][4] = {};

    const int NSTEP = H1 / 32;  // 12
    #pragma unroll
    for (int p = 0; p < 3; ++p) {
        size_t ko = (size_t)p * 32;
        int lb = p * 4096;
        gll16(gA0 + ko, &As[lb + chunk0]); gll16(gA1 + ko, &As[lb + chunk1]);
        gll16(gB0 + ko, &Bs[lb + chunk0]); gll16(gB1 + ko, &Bs[lb + chunk1]);
    }
    int cur = 0;
    for (int st = 0; st < NSTEP; ++st) {
        const int rem = NSTEP - 1 - st;
        if (rem >= 2)      asm volatile("s_waitcnt vmcnt(8)" ::: "memory");
        else if (rem == 1) asm volatile("s_waitcnt vmcnt(4)" ::: "memory");
        else               asm volatile("s_waitcnt vmcnt(0)" ::: "memory");
        __builtin_amdgcn_s_barrier();
        __builtin_amdgcn_sched_barrier(0);
        const int lb = cur * 4096;
        bf16x8 af[4], bfr[4];
        #pragma unroll
        for (int mi = 0; mi < 4; ++mi) {
            int r = wm * 64 + mi * 16 + rsub;
            int phys = r * 4 + (kq ^ ((r >> 1) & 3));
            af[mi] = *(const bf16x8*)&As[lb + phys * 8];
        }
        #pragma unroll
        for (int ni = 0; ni < 4; ++ni) {
            int r = wn * 64 + ni * 16 + rsub;
            int phys = r * 4 + (kq ^ ((r >> 1) & 3));
            bfr[ni] = *(const bf16x8*)&Bs[lb + phys * 8];
        }
        #pragma unroll
        for (int mi = 0; mi < 4; ++mi)
            #pragma unroll
            for (int ni = 0; ni < 4; ++ni)
                acc[mi][ni] = __builtin_amdgcn_mfma_f32_16x16x32_bf16(
                    af[mi], bfr[ni], acc[mi][ni], 0, 0, 0);
        __builtin_amdgcn_sched_barrier(0);
        __builtin_amdgcn_s_barrier();
        __builtin_amdgcn_sched_barrier(0);
        if (st + 3 < NSTEP) {
            size_t ko = (size_t)(st + 3) * 32;
            gll16(gA0 + ko, &As[lb + chunk0]);
            gll16(gA1 + ko, &As[lb + chunk1]);
            gll16(gB0 + ko, &Bs[lb + chunk0]);
            gll16(gB1 + ko, &Bs[lb + chunk1]);
        }
        cur = (cur == 2) ? 0 : cur + 1;
    }
    #pragma unroll
    for (int mi = 0; mi < 4; ++mi) {
        int rowb = m0 + wm * 64 + mi * 16 + kq * 4;
        #pragma unroll
        for (int ni = 0; ni < 4; ++ni) {
            int col = n0 + wn * 64 + ni * 16 + rsub;
            float bcol = bias[col];
            #pragma unroll
            for (int r = 0; r < 4; ++r) {
                int row = rowb + r;
                int g = row >> 13, s = (row >> 10) & 7, n = row & 1023;
                int dcol = 2 + (lv0 + g) * H2 + col;
                out[((size_t)n * SN + s) * DOUT + dcol] =
                    acc[mi][ni][r] + bcol + te[s * DOUT + dcol];
            }
        }
    }
}

// ---------------------------------------------------------------------------
// Transpose + bf16-convert: in (K x Nw f32) -> out (Nw x Kp bf16), zero-pad.
// ---------------------------------------------------------------------------
__global__ __launch_bounds__(256) void conv_t_kernel(
    const float* __restrict__ in, unsigned short* __restrict__ outp,
    int K, int Nw, int Kp)
{
    __shared__ float tile[32][33];
    const int kb = blockIdx.x * 32, nb = blockIdx.y * 32;
    const int tx = threadIdx.x & 31, ty = threadIdx.x >> 5;
    #pragma unroll
    for (int i = 0; i < 32; i += 8) {
        int k = kb + ty + i, nn = nb + tx;
        tile[ty + i][tx] = (k < K && nn < Nw) ? in[(size_t)k * Nw + nn] : 0.f;
    }
    __syncthreads();
    #pragma unroll
    for (int i = 0; i < 32; i += 8) {
        int nn = nb + ty + i, k = kb + tx;
        if (nn < Nw) outp[(size_t)nn * Kp + k] = f2b(tile[tx][ty + i]);
    }
}

// Kernel D: vis, conf, rel_emb(84) + time_emb.
__global__ __launch_bounds__(128) void tail_kernel(
    const float* __restrict__ coords, const float* __restrict__ vis,
    const float* __restrict__ conf, const float* __restrict__ te,
    float* __restrict__ out)
{
    const int b = blockIdx.x;
    const int n = b >> 3, s = b & 7;
    const int d = threadIdx.x;
    if (d >= 86) return;
    const size_t ob = (size_t)b * DOUT;
    if (d == 0) {
        out[ob + 0] = vis[(size_t)s * NN + n] + te[s * DOUT + 0];
    } else if (d == 1) {
        out[ob + 1] = conf[(size_t)s * NN + n] + te[s * DOUT + 1];
    } else {
        int rd = d - 2;
        float cx = coords[((size_t)s * NN + n) * 2 + 0];
        float cy = coords[((size_t)s * NN + n) * 2 + 1];
        float rfx = 0.f, rfy = 0.f, rbx = 0.f, rby = 0.f;
        if (s < SN - 1) {
            rfx = cx - coords[((size_t)(s + 1) * NN + n) * 2 + 0];
            rfy = cy - coords[((size_t)(s + 1) * NN + n) * 2 + 1];
        }
        if (s > 0) {
            rbx = cx - coords[((size_t)(s - 1) * NN + n) * 2 + 0];
            rby = cy - coords[((size_t)(s - 1) * NN + n) * 2 + 1];
        }
        float r4[4] = {rfx / 128.f, rfy / 96.f, rbx / 128.f, rby / 96.f};
        float val;
        if (rd < 4) {
            val = r4[rd];
        } else if (rd < 44) {
            int q = rd - 4; int deg = q >> 2, comp = q & 3;
            val = sinf(r4[comp] * (float)(1 << deg));
        } else {
            int q = rd - 44; int deg = q >> 2, comp = q & 3;
            val = sinf(r4[comp] * (float)(1 << deg) + 1.57079632679489662f);
        }
        int od = 1026 + rd;
        out[ob + od] = val + te[s * DOUT + od];
    }
}

extern "C" void kernel_launch(void* const* d_in, const int* in_sizes, int n_in,
                              void* d_out, int out_size, void* d_ws, size_t ws_size,
                              hipStream_t stream) {
    const float* fmaps[4] = {(const float*)d_in[0], (const float*)d_in[2],
                             (const float*)d_in[4], (const float*)d_in[6]};
    const float* track[4] = {(const float*)d_in[1], (const float*)d_in[3],
                             (const float*)d_in[5], (const float*)d_in[7]};
    const float* coords = (const float*)d_in[8];
    const float* vis    = (const float*)d_in[9];
    const float* conf   = (const float*)d_in[10];
    const float* w1     = (const float*)d_in[11];
    const float* b1     = (const float*)d_in[12];
    const float* w2     = (const float*)d_in[13];
    const float* b2     = (const float*)d_in[14];
    const float* te     = (const float*)d_in[15];
    float* out = (float*)d_out;

    const int Hs[4] = {96, 48, 24, 12};
    const int Ws[4] = {128, 64, 32, 16};

    // ---- workspace layout ----
    char* wsb = (char*)d_ws;
    unsigned short* w1t = (unsigned short*)wsb;
    size_t off = (size_t)H1 * K1P * 2;
    unsigned short* w2t = (unsigned short*)(wsb + off);
    off += (size_t)H2 * H1 * 2;
    unsigned short* fpad[4];
    for (int l = 0; l < 4; ++l) {
        fpad[l] = (unsigned short*)(wsb + off);
        off += (size_t)SN * (Hs[l] + 8) * (Ws[l] + 8) * CC * 2;
    }
    off += 512;  // slack
    const size_t fixed = off;
    int n_lv = 4;
    while (n_lv > 1 &&
           fixed + (size_t)n_lv * SN * NN * (K1P + H1) * 2 > ws_size)
        n_lv >>= 1;
    unsigned short* volb = (unsigned short*)(wsb + fixed);
    unsigned short* hb   = volb + (size_t)n_lv * SN * NN * K1P;

    // ---- weight prep + fmap conversion ----
    conv_t_kernel<<<dim3(K1P / 32, H1 / 32), 256, 0, stream>>>(w1, w1t, 2401, H1, K1P);
    conv_t_kernel<<<dim3(H1 / 32, H2 / 32), 256, 0, stream>>>(w2, w2t, H1, H2, H1);
    for (int l = 0; l < 4; ++l)
        conv_fmap_kernel<<<SN * (Hs[l] + 8), 256, 0, stream>>>(
            fmaps[l], fpad[l], Hs[l], Ws[l]);

    for (int lv0 = 0; lv0 < 4; lv0 += n_lv) {
        sample_vol_kernel<<<n_lv * NN, 256, 0, stream>>>(
            fpad[0], fpad[1], fpad[2], fpad[3],
            track[0], track[1], track[2], track[3],
            coords, volb, lv0);
        const int rows = n_lv * SN * NN;
        gemm1_kernel<<<(rows / 128) * 3, 256, 0, stream>>>(volb, w1t, b1, hb);
        gemm2_kernel<<<(rows / 128) * 2, 256, 0, stream>>>(hb, w2t, b2, te, out, lv0);
    }
    tail_kernel<<<SN * NN, 128, 0, stream>>>(coords, vis, conf, te, out);
}